// Round 1
// baseline (1168.120 us; speedup 1.0000x reference)
//
#include <hip/hip_runtime.h>

#define NN 100000
#define NE 3200000
#define DD 128
#define KC 10
#define NITER 10
#define NB 128   // blocks for k_sum partials

// ---------------- kmeans ----------------

__global__ void k_init_c(const float* __restrict__ x, float* __restrict__ c,
                         float* __restrict__ cnorm) {
  const int j = blockIdx.x, k = threadIdx.x;  // <<<KC, DD>>>
  float v = x[j * DD + k];
  c[j * DD + k] = v;
  __shared__ float red[DD];
  red[k] = v * v;
  __syncthreads();
  for (int s = DD / 2; s > 0; s >>= 1) {
    if (k < s) red[k] += red[k + s];
    __syncthreads();
  }
  if (k == 0) cnorm[j] = red[0];
}

__global__ __launch_bounds__(256) void k_assign(const float* __restrict__ x,
                                                const float* __restrict__ c,
                                                const float* __restrict__ cnorm,
                                                int* __restrict__ cl) {
  __shared__ float cs[KC][DD];
  __shared__ float cn[KC];
  for (int i = threadIdx.x; i < KC * DD; i += 256) ((float*)cs)[i] = c[i];
  if (threadIdx.x < KC) cn[threadIdx.x] = cnorm[threadIdx.x];
  __syncthreads();
  const int n = blockIdx.x * 256 + threadIdx.x;
  if (n >= NN) return;
  const float4* __restrict__ xr = (const float4*)(x + (size_t)n * DD);
  float dot[KC];
#pragma unroll
  for (int j = 0; j < KC; ++j) dot[j] = 0.f;
#pragma unroll 4
  for (int k4 = 0; k4 < DD / 4; ++k4) {
    const float4 xv = xr[k4];
#pragma unroll
    for (int j = 0; j < KC; ++j) {
      const float4 cv = *(const float4*)&cs[j][k4 * 4];
      dot[j] += xv.x * cv.x + xv.y * cv.y + xv.z * cv.z + xv.w * cv.w;
    }
  }
  // d_j = -2*dot_j + |c_j|^2 ; argmin, first index wins ties (strict <)
  int best = 0;
  float bd = cn[0] - 2.f * dot[0];
#pragma unroll
  for (int j = 1; j < KC; ++j) {
    const float dj = cn[j] - 2.f * dot[j];
    if (dj < bd) { bd = dj; best = j; }
  }
  cl[n] = best;
}

// wave-cooperative segment sum: lane L owns columns 2L, 2L+1; cluster id is
// wave-uniform per node => conflict-free non-atomic LDS accumulation.
__global__ __launch_bounds__(256) void k_sum(const float* __restrict__ x,
                                             const int* __restrict__ cl,
                                             float* __restrict__ sumpart,
                                             int* __restrict__ cntpart) {
  __shared__ float2 wsum[4][KC][DD / 2];
  __shared__ int wcnt[4][KC];
  float* wsf = (float*)wsum;
  for (int i = threadIdx.x; i < 4 * KC * DD; i += 256) wsf[i] = 0.f;
  if (threadIdx.x < 4 * KC) ((int*)wcnt)[threadIdx.x] = 0;
  __syncthreads();
  const int w = threadIdx.x >> 6, lane = threadIdx.x & 63;
  const int gw = blockIdx.x * 4 + w, nw = gridDim.x * 4;
  const float2* __restrict__ x2 = (const float2*)x;
  for (int n = gw; n < NN; n += nw) {
    const int j = cl[n];                       // wave-uniform
    const float2 v = x2[(size_t)n * (DD / 2) + lane];
    float2 t = wsum[w][j][lane];
    t.x += v.x;
    t.y += v.y;
    wsum[w][j][lane] = t;
    if (lane == 0) wcnt[w][j] += 1;
  }
  __syncthreads();
  for (int i = threadIdx.x; i < KC * DD; i += 256)
    sumpart[(size_t)blockIdx.x * (KC * DD) + i] =
        wsf[i] + wsf[KC * DD + i] + wsf[2 * KC * DD + i] + wsf[3 * KC * DD + i];
  if (threadIdx.x < KC)
    cntpart[blockIdx.x * KC + threadIdx.x] =
        wcnt[0][threadIdx.x] + wcnt[1][threadIdx.x] + wcnt[2][threadIdx.x] +
        wcnt[3][threadIdx.x];
}

__global__ void k_update(const float* __restrict__ sumpart,
                         const int* __restrict__ cntpart, float* __restrict__ c,
                         float* __restrict__ cnorm) {
  const int j = blockIdx.x, k = threadIdx.x;  // <<<KC, DD>>>
  __shared__ float red[DD];
  // reduce counts
  float cf = 0.f;
  for (int b = k; b < NB; b += DD) cf += (float)cntpart[b * KC + j];
  red[k] = cf;
  __syncthreads();
  for (int s = DD / 2; s > 0; s >>= 1) {
    if (k < s) red[k] += red[k + s];
    __syncthreads();
  }
  const float denom = fmaxf(red[0], 1.0f);
  __syncthreads();
  // reduce sums
  float s0 = 0.f;
#pragma unroll 8
  for (int b = 0; b < NB; ++b) s0 += sumpart[(size_t)b * (KC * DD) + j * DD + k];
  const float cj = s0 / denom;
  c[j * DD + k] = cj;
  red[k] = cj * cj;
  __syncthreads();
  for (int s = DD / 2; s > 0; s >>= 1) {
    if (k < s) red[k] += red[k + s];
    __syncthreads();
  }
  if (k == 0) cnorm[j] = red[0];
}

// ------------- centroid attention (10x10) -------------

__global__ __launch_bounds__(DD) void k_ca(const float* __restrict__ c,
                                           const float* __restrict__ WQ,
                                           const float* __restrict__ WV,
                                           float* __restrict__ CA) {
  __shared__ float cs[KC][DD], q[KC][DD], v[KC][DD], pr[KC][KC];
  const int k = threadIdx.x;  // <<<1, DD>>>
  for (int i = 0; i < KC; ++i) cs[i][k] = c[i * DD + k];
  __syncthreads();
  for (int i = 0; i < KC; ++i) {
    float aq = 0.f, av = 0.f;
    for (int m = 0; m < DD; ++m) {
      const float cm = cs[i][m];
      aq += cm * WQ[m * DD + k];
      av += cm * WV[m * DD + k];
    }
    q[i][k] = aq;
    v[i][k] = av;
  }
  __syncthreads();
  if (k < KC * KC) {
    const int i = k / KC, l = k % KC;
    float acc = 0.f;
    for (int m = 0; m < DD; ++m) acc += q[i][m] * v[l][m];
    pr[i][l] = acc / sqrtf((float)DD);
  }
  __syncthreads();
  if (k < KC) {
    float mx = pr[k][0];
    for (int l = 1; l < KC; ++l) mx = fmaxf(mx, pr[k][l]);
    float e[KC];
    float s = 0.f;
    for (int l = 0; l < KC; ++l) {
      e[l] = expf(pr[k][l] - mx);
      s += e[l];
    }
    for (int l = 0; l < KC; ++l) CA[k * KC + l] = e[l] / s;
  }
}

// ------------- edge histogram + per-node table + gather -------------

__global__ __launch_bounds__(256) void k_cnt(const int* __restrict__ e0,
                                             const int* __restrict__ e1,
                                             const int* __restrict__ cl,
                                             int* __restrict__ cnt) {
  const int e = blockIdx.x * 256 + threadIdx.x;
  if (e >= NE) return;
  atomicAdd(&cnt[(size_t)e0[e] * KC + cl[e1[e]]], 1);
}

__global__ __launch_bounds__(256) void k_tab(const int* __restrict__ cl,
                                             const int* __restrict__ cnt,
                                             const float* __restrict__ CA,
                                             float* __restrict__ tab) {
  __shared__ float cas[KC * KC];
  if (threadIdx.x < KC * KC) cas[threadIdx.x] = CA[threadIdx.x];
  __syncthreads();
  const int n = blockIdx.x * 256 + threadIdx.x;
  if (n >= NN) return;
  const int s = cl[n];
  const float* car = &cas[s * KC];
  int cj[KC];
#pragma unroll
  for (int j = 0; j < KC; ++j) cj[j] = cnt[(size_t)n * KC + j];
  float m = -INFINITY;
#pragma unroll
  for (int j = 0; j < KC; ++j)
    if (cj[j] > 0) m = fmaxf(m, car[j]);
  if (m == -INFINITY) {  // no out-edges: never gathered, write zeros
#pragma unroll
    for (int j = 0; j < KC; ++j) tab[(size_t)n * KC + j] = 0.f;
    return;
  }
  float sum = 0.f;
#pragma unroll
  for (int j = 0; j < KC; ++j)
    if (cj[j] > 0) sum += (float)cj[j] * expf(car[j] - m);
  const float den = sum + 1e-16f;
#pragma unroll
  for (int j = 0; j < KC; ++j) tab[(size_t)n * KC + j] = expf(car[j] - m) / den;
}

__global__ __launch_bounds__(256) void k_gather(const int* __restrict__ e0,
                                                const int* __restrict__ e1,
                                                const int* __restrict__ cl,
                                                const float* __restrict__ tab,
                                                float* __restrict__ out) {
  const int e = blockIdx.x * 256 + threadIdx.x;
  if (e >= NE) return;
  out[e] = tab[(size_t)e0[e] * KC + cl[e1[e]]];
}

// ---------------- launch ----------------

extern "C" void kernel_launch(void* const* d_in, const int* in_sizes, int n_in,
                              void* d_out, int out_size, void* d_ws,
                              size_t ws_size, hipStream_t stream) {
  const float* x = (const float*)d_in[0];
  const int* edge = (const int*)d_in[1];
  const float* WQ = (const float*)d_in[2];
  const float* WV = (const float*)d_in[3];
  // d_in[4] = WK, only used for its shape in the reference
  float* out = (float*)d_out;
  const int* e0 = edge;
  const int* e1 = edge + NE;

  float* ws = (float*)d_ws;
  float* c = ws;                       // 1280
  float* cnorm = ws + 1280;            // 16 (padded)
  float* CA = ws + 1296;               // 112 (padded)
  float* sumpart = ws + 1408;          // NB*KC*DD = 163840
  float* tab = sumpart + NB * KC * DD; // NN*KC = 1,000,000
  int* cl = (int*)(tab + (size_t)NN * KC);  // 100,000
  int* cntpart = cl + NN;              // NB*KC = 1280
  int* cnt = cntpart + NB * KC;        // NN*KC = 1,000,000
  // total ~9.1 MB of d_ws

  hipMemsetAsync(cnt, 0, (size_t)NN * KC * sizeof(int), stream);

  k_init_c<<<KC, DD, 0, stream>>>(x, c, cnorm);
  for (int it = 0; it < NITER; ++it) {
    k_assign<<<(NN + 255) / 256, 256, 0, stream>>>(x, c, cnorm, cl);
    k_sum<<<NB, 256, 0, stream>>>(x, cl, sumpart, cntpart);
    k_update<<<KC, DD, 0, stream>>>(sumpart, cntpart, c, cnorm);
  }
  k_ca<<<1, DD, 0, stream>>>(c, WQ, WV, CA);
  k_cnt<<<(NE + 255) / 256, 256, 0, stream>>>(e0, e1, cl, cnt);
  k_tab<<<(NN + 255) / 256, 256, 0, stream>>>(cl, cnt, CA, tab);
  k_gather<<<(NE + 255) / 256, 256, 0, stream>>>(e0, e1, cl, tab, out);
}